// Round 9
// baseline (182.845 us; speedup 1.0000x reference)
//
#include <hip/hip_runtime.h>

#define CC 128
#define NN 4096
#define NB 2
#define NSPLIT 8
#define TK 64
#define ITERS 8    // 512 keys per split / TK

typedef unsigned short ushort;
typedef unsigned int uint;
typedef __attribute__((ext_vector_type(8))) _Float16 h8;  // 8 f16 (4 VGPRs)
typedef __attribute__((ext_vector_type(8))) short s8;     // 8 bf16 (4 VGPRs)
typedef __attribute__((ext_vector_type(4))) float f4;     // 4 fp32 acc
#define MFMA16(a, b, c) __builtin_amdgcn_mfma_f32_16x16x32_f16(a, b, c, 0, 0, 0)
#define MFMAB(a, b, c)  __builtin_amdgcn_mfma_f32_16x16x32_bf16(a, b, c, 0, 0, 0)

__device__ __forceinline__ ushort f2h(float f) {
  _Float16 h = (_Float16)f;
  return *(ushort*)&h;
}
__device__ __forceinline__ ushort f2bf(float f) {
  uint u = __float_as_uint(f);
  u += 0x7fffu + ((u >> 16) & 1u);   // round-to-nearest-even
  return (ushort)(u >> 16);
}
__device__ __forceinline__ float bf2f(ushort u) {
  return __uint_as_float((uint)u << 16);
}

// ---------------- kernel A: q/k/v projections, SPLIT BY WHICH (R20, verified) --------
__global__ __launch_bounds__(256) void qkv_mm(
    const float* __restrict__ x, const float* __restrict__ Wq,
    const float* __restrict__ Wk, const float* __restrict__ Wv,
    ushort* __restrict__ qT, ushort* __restrict__ kT, ushort* __restrict__ vB,
    float* __restrict__ stats) {
  __shared__ ushort Wh[CC][136];     // fp16 W, +8 pad (2-way banks = free)
  __shared__ ushort xs[32][136];     // fp16 x^T tile [n][c]
  const int t = threadIdx.x;
  const int n0 = blockIdx.x * 32;
  const int b = blockIdx.y;
  const int which = blockIdx.z;

  if (blockIdx.x == 0 && b == 0 && which == 0 && t < 32) stats[t] = 0.f;

  {  // stage x tile with 4x4 register transpose: one slot per thread (verified)
    int c0 = (t & 31) * 4;
    int n4 = (t >> 5) * 4;
    float4 r0 = *(const float4*)&x[((size_t)b * CC + c0 + 0) * NN + n0 + n4];
    float4 r1 = *(const float4*)&x[((size_t)b * CC + c0 + 1) * NN + n0 + n4];
    float4 r2 = *(const float4*)&x[((size_t)b * CC + c0 + 2) * NN + n0 + n4];
    float4 r3 = *(const float4*)&x[((size_t)b * CC + c0 + 3) * NN + n0 + n4];
    ushort4 w0, w1, w2, w3;
    w0.x = f2h(r0.x); w0.y = f2h(r1.x); w0.z = f2h(r2.x); w0.w = f2h(r3.x);
    w1.x = f2h(r0.y); w1.y = f2h(r1.y); w1.z = f2h(r2.y); w1.w = f2h(r3.y);
    w2.x = f2h(r0.z); w2.y = f2h(r1.z); w2.z = f2h(r2.z); w2.w = f2h(r3.z);
    w3.x = f2h(r0.w); w3.y = f2h(r1.w); w3.z = f2h(r2.w); w3.w = f2h(r3.w);
    *(ushort4*)&xs[n4 + 0][c0] = w0;
    *(ushort4*)&xs[n4 + 1][c0] = w1;
    *(ushort4*)&xs[n4 + 2][c0] = w2;
    *(ushort4*)&xs[n4 + 3][c0] = w3;
  }

  {  // stage this block's W: fp32 -> fp16, coalesced (verified body)
    const float* W = (which == 0) ? Wq : (which == 1) ? Wk : Wv;
#pragma unroll
    for (int i = 0; i < 16; ++i) {
      int slot = t + 256 * i;
      int o = slot >> 5, c4 = (slot & 31) * 4;
      float4 w4 = *(const float4*)&W[o * CC + c4];
      ushort4 p; p.x = f2h(w4.x); p.y = f2h(w4.y); p.z = f2h(w4.z); p.w = f2h(w4.w);
      *(ushort4*)&Wh[o][c4] = p;
    }
  }
  __syncthreads();                     // xs + Wh ready; no more barriers

  const int wv = t >> 6, lane = t & 63;
  const int quad = lane >> 4, l16 = lane & 15;

  if (which < 2) {                     // q,k: D[o][n]  (verified R17 body)
    ushort* out = which ? kT : qT;
    f4 acc[2][2];
#pragma unroll
    for (int ot = 0; ot < 2; ++ot)
#pragma unroll
      for (int nt = 0; nt < 2; ++nt) acc[ot][nt] = (f4){0.f, 0.f, 0.f, 0.f};
#pragma unroll
    for (int kk = 0; kk < 4; ++kk) {
      h8 a0 = *(const h8*)&Wh[(wv * 2 + 0) * 16 + l16][kk * 32 + quad * 8];
      h8 a1 = *(const h8*)&Wh[(wv * 2 + 1) * 16 + l16][kk * 32 + quad * 8];
#pragma unroll
      for (int nt = 0; nt < 2; ++nt) {
        h8 bb = *(const h8*)&xs[nt * 16 + l16][kk * 32 + quad * 8];
        acc[0][nt] = MFMA16(a0, bb, acc[0][nt]);
        acc[1][nt] = MFMA16(a1, bb, acc[1][nt]);
      }
    }
#pragma unroll
    for (int ot = 0; ot < 2; ++ot)
#pragma unroll
      for (int nt = 0; nt < 2; ++nt) {
        f4 a = acc[ot][nt];
        ushort4 p; p.x = f2h(a[0]); p.y = f2h(a[1]); p.z = f2h(a[2]); p.w = f2h(a[3]);
        *(ushort4*)&out[((size_t)b * NN + n0 + nt * 16 + l16) * CC +
                        (wv * 2 + ot) * 16 + quad * 4] = p;
      }
  } else {                             // v: D[n][c]  (verified R17 body)
    f4 acc[2][2];
#pragma unroll
    for (int ci = 0; ci < 2; ++ci)
#pragma unroll
      for (int nt = 0; nt < 2; ++nt) acc[ci][nt] = (f4){0.f, 0.f, 0.f, 0.f};
#pragma unroll
    for (int kk = 0; kk < 4; ++kk) {
      h8 a0 = *(const h8*)&xs[0 * 16 + l16][kk * 32 + quad * 8];
      h8 a1 = *(const h8*)&xs[1 * 16 + l16][kk * 32 + quad * 8];
      h8 b0 = *(const h8*)&Wh[(wv * 2 + 0) * 16 + l16][kk * 32 + quad * 8];
      h8 b1 = *(const h8*)&Wh[(wv * 2 + 1) * 16 + l16][kk * 32 + quad * 8];
      acc[0][0] = MFMA16(a0, b0, acc[0][0]);
      acc[0][1] = MFMA16(a1, b0, acc[0][1]);
      acc[1][0] = MFMA16(a0, b1, acc[1][0]);
      acc[1][1] = MFMA16(a1, b1, acc[1][1]);
    }
#pragma unroll
    for (int ci = 0; ci < 2; ++ci)
#pragma unroll
      for (int nt = 0; nt < 2; ++nt) {
        f4 a = acc[ci][nt];
        ushort4 p; p.x = f2bf(a[0]); p.y = f2bf(a[1]); p.z = f2bf(a[2]); p.w = f2bf(a[3]);
        *(ushort4*)&vB[((size_t)b * CC + (wv * 2 + ci) * 16 + l16) * NN +
                       n0 + nt * 16 + quad * 4] = p;
      }
  }
}

// ---------------- kernel B: 8-way split-K flash (R17/R20, verified) ----------------
__global__ __launch_bounds__(256) void attn_split(
    const ushort* __restrict__ qTg, const ushort* __restrict__ kTg,
    const ushort* __restrict__ vBg, ushort* __restrict__ Op,
    float* __restrict__ Lg) {
  __shared__ ushort ksT[TK][136];      // [m][c] fp16, 17 KB
  __shared__ ushort vs[CC][72];        // [c][m] bf16, 18 KB
  __shared__ ushort psb[4][32][72];    // per-wave P [q][m] bf16, 18 KB

  const int t = threadIdx.x;
  const int b = blockIdx.z;
  const int split = blockIdx.y;
  const int n0 = blockIdx.x * 128;
  const int wv = t >> 6;
  const int lane = t & 63;
  const int quad = lane >> 4;
  const int l16 = lane & 15;
  const int nw = n0 + wv * 32;
  const int m00 = split * (NN / NSPLIT);

  const int krow = t >> 4, kcol = (t & 15) * 8;
  const int vrow = t >> 3, vcol = (t & 7) * 8;
  const ushort* kbp = kTg + ((size_t)b * NN + m00 + krow) * CC + kcol;
  const ushort* vbp = vBg + ((size_t)b * CC + vrow) * NN + m00 + vcol;

  const size_t qb0 = ((size_t)b * NN + nw + l16) * CC + quad * 8;
  const size_t qb1 = qb0 + (size_t)16 * CC;
  h8 aq[2][4];
#pragma unroll
  for (int kk = 0; kk < 4; ++kk) {
    aq[0][kk] = *(const h8*)&qTg[qb0 + kk * 32];
    aq[1][kk] = *(const h8*)&qTg[qb1 + kk * 32];
  }

  int4 k0 = *(const int4*)&kbp[0];
  int4 k1 = *(const int4*)&kbp[16 * CC];
  int4 k2 = *(const int4*)&kbp[32 * CC];
  int4 k3 = *(const int4*)&kbp[48 * CC];
  int4 v0 = *(const int4*)&vbp[0];
  int4 v1 = *(const int4*)&vbp[(size_t)32 * NN];
  int4 v2 = *(const int4*)&vbp[(size_t)64 * NN];
  int4 v3 = *(const int4*)&vbp[(size_t)96 * NN];

  s8 ones;
#pragma unroll
  for (int i = 0; i < 8; ++i) ones[i] = (short)0x3F80;  // bf16 1.0

  f4 o[2][8];
#pragma unroll
  for (int j = 0; j < 2; ++j)
#pragma unroll
    for (int ct = 0; ct < 8; ++ct) o[j][ct] = (f4){0.f, 0.f, 0.f, 0.f};
  f4 oL[2];
  oL[0] = (f4){0.f, 0.f, 0.f, 0.f};
  oL[1] = (f4){0.f, 0.f, 0.f, 0.f};

  for (int kt = 0; kt < ITERS; ++kt) {
    *(int4*)&ksT[krow][kcol]      = k0;
    *(int4*)&ksT[krow + 16][kcol] = k1;
    *(int4*)&ksT[krow + 32][kcol] = k2;
    *(int4*)&ksT[krow + 48][kcol] = k3;
    *(int4*)&vs[vrow][vcol]       = v0;
    *(int4*)&vs[vrow + 32][vcol]  = v1;
    *(int4*)&vs[vrow + 64][vcol]  = v2;
    *(int4*)&vs[vrow + 96][vcol]  = v3;
    __syncthreads();                   // K,V ready

    {  // prefetch next tile (drains over compute)
      int ktn = (kt + 1 < ITERS) ? kt + 1 : kt;
      const ushort* kp = kbp + (size_t)ktn * TK * CC;
      const ushort* vp = vbp + (size_t)ktn * TK;
      k0 = *(const int4*)&kp[0];
      k1 = *(const int4*)&kp[16 * CC];
      k2 = *(const int4*)&kp[32 * CC];
      k3 = *(const int4*)&kp[48 * CC];
      v0 = *(const int4*)&vp[0];
      v1 = *(const int4*)&vp[(size_t)32 * NN];
      v2 = *(const int4*)&vp[(size_t)64 * NN];
      v3 = *(const int4*)&vp[(size_t)96 * NN];
    }

    // scores TRANSPOSED: D = S^T[m][q]; A=K-frag (LDS, shared across j), B=Q.
    f4 s[2][4];
#pragma unroll
    for (int j = 0; j < 2; ++j)
#pragma unroll
      for (int mt = 0; mt < 4; ++mt) s[j][mt] = (f4){0.f, 0.f, 0.f, 0.f};
#pragma unroll
    for (int kk = 0; kk < 4; ++kk) {
      h8 b0 = *(const h8*)&ksT[ 0 + l16][kk * 32 + quad * 8];
      h8 b1 = *(const h8*)&ksT[16 + l16][kk * 32 + quad * 8];
      h8 b2 = *(const h8*)&ksT[32 + l16][kk * 32 + quad * 8];
      h8 b3 = *(const h8*)&ksT[48 + l16][kk * 32 + quad * 8];
#pragma unroll
      for (int j = 0; j < 2; ++j) {
        s[j][0] = MFMA16(b0, aq[j][kk], s[j][0]);
        s[j][1] = MFMA16(b1, aq[j][kk], s[j][1]);
        s[j][2] = MFMA16(b2, aq[j][kk], s[j][2]);
        s[j][3] = MFMA16(b3, aq[j][kk], s[j][3]);
      }
    }

    // max-free softmax: exp + packed b64 psb stores (8 stores for 32 q-rows)
#pragma unroll
    for (int j = 0; j < 2; ++j)
#pragma unroll
      for (int mt = 0; mt < 4; ++mt) {
        ushort4 pk;
        pk.x = f2bf(__expf(s[j][mt][0]));
        pk.y = f2bf(__expf(s[j][mt][1]));
        pk.z = f2bf(__expf(s[j][mt][2]));
        pk.w = f2bf(__expf(s[j][mt][3]));
        *(ushort4*)&psb[wv][j * 16 + l16][mt * 16 + quad * 4] = pk;
      }
    // same-wave DS is in-order: psb writes visible to reads below

    // PV (bf16): V-frags shared across both q-subtiles
#pragma unroll
    for (int mk = 0; mk < 2; ++mk) {
      s8 bp0 = *(const s8*)&psb[wv][ 0 + l16][mk * 32 + quad * 8];
      s8 bp1 = *(const s8*)&psb[wv][16 + l16][mk * 32 + quad * 8];
#pragma unroll
      for (int ct = 0; ct < 8; ++ct) {
        s8 a = *(const s8*)&vs[ct * 16 + l16][mk * 32 + quad * 8];
        o[0][ct] = MFMAB(a, bp0, o[0][ct]);
        o[1][ct] = MFMAB(a, bp1, o[1][ct]);
      }
      oL[0] = MFMAB(ones, bp0, oL[0]);
      oL[1] = MFMAB(ones, bp1, oL[1]);
    }
    __syncthreads();                   // all waves done reading ksT/vs
  }

  // epilogue: bf16 O partial [split*NB+b][n][c], packed 8B stores, both subtiles
#pragma unroll
  for (int j = 0; j < 2; ++j) {
    if (quad == 0)
      Lg[((size_t)(split * NB + b)) * NN + nw + j * 16 + l16] = oL[j][0];
    size_t nb_ = ((size_t)(split * NB + b) * NN + nw + j * 16 + l16) * CC + quad * 4;
    ushort4 p;
#pragma unroll
    for (int ct = 0; ct < 8; ++ct) {
      f4 a = o[j][ct];
      p.x = f2bf(a[0]); p.y = f2bf(a[1]); p.z = f2bf(a[2]); p.w = f2bf(a[3]);
      *(ushort4*)&Op[nb_ + ct * 16] = p;
    }
  }
}

// ---------------- kernel C: combine 8 splits + Wo projection + residual + GN stats ----
// R22: 16-n tiles -> grid (NN/16, NB) = 512 blocks = 2 blocks/CU = 8 waves/CU
// (was 32-n, 256 blocks, 1/CU). R21's profile showed this kernel latency-bound at
// 10% occupancy (HBM 8%, VALUBusy 3.8%): doubling resident waves + halving
// per-block serial work attacks exactly that. Same verified access patterns,
// nt-dimension removed. No fused GN (R21's barrier cost +10 us — reverted).
__global__ __launch_bounds__(256) void proj_mm(
    const float* __restrict__ x, const float* __restrict__ Wo,
    const ushort* __restrict__ Op, const float* __restrict__ Lg,
    float* __restrict__ y, float* __restrict__ stats) {
  __shared__ ushort Wh[CC][136];
  __shared__ ushort hT[16][136];
  __shared__ float Linv[16];
  const int t = threadIdx.x;
  const int n0 = blockIdx.x * 16;
  const int b = blockIdx.y;

#pragma unroll
  for (int i = 0; i < 16; ++i) {       // stage Wo -> fp16
    int slot = t + 256 * i;
    int o = slot >> 5, c4 = (slot & 31) * 4;
    float4 w4 = *(const float4*)&Wo[o * CC + c4];
    ushort4 p; p.x = f2h(w4.x); p.y = f2h(w4.y); p.z = f2h(w4.z); p.w = f2h(w4.w);
    *(ushort4*)&Wh[o][c4] = p;
  }
  if (t < 16) {
    float l = 0.f;
#pragma unroll
    for (int s = 0; s < NSPLIT; ++s)
      l += Lg[(size_t)(s * NB + b) * NN + n0 + t];
    Linv[t] = 1.f / l;
  }
  __syncthreads();

#pragma unroll
  for (int i = 0; i < 2; ++i) {        // combine 8 bf16 splits -> h^T fp16 (16 rows)
    int slot = t + 256 * i;
    int n = slot >> 5, c4 = (slot & 31) * 4;
    size_t base = ((size_t)(n0 + n)) * CC + c4;
    float a0 = 0.f, a1 = 0.f, a2 = 0.f, a3 = 0.f;
#pragma unroll
    for (int s = 0; s < NSPLIT; ++s) {
      ushort4 u = *(const ushort4*)&Op[(size_t)(s * NB + b) * NN * CC + base];
      a0 += bf2f(u.x); a1 += bf2f(u.y); a2 += bf2f(u.z); a3 += bf2f(u.w);
    }
    float li = Linv[n];
    ushort4 p;
    p.x = f2h(a0 * li); p.y = f2h(a1 * li);
    p.z = f2h(a2 * li); p.w = f2h(a3 * li);
    *(ushort4*)&hT[n][c4] = p;
  }
  __syncthreads();

  const int wv = t >> 6, lane = t & 63;
  const int quad = lane >> 4, l16 = lane & 15;

  f4 acc[2];                           // [ot] — single 16-n tile
  acc[0] = (f4){0.f, 0.f, 0.f, 0.f};
  acc[1] = (f4){0.f, 0.f, 0.f, 0.f};
#pragma unroll
  for (int kk = 0; kk < 4; ++kk) {
    h8 a = *(const h8*)&hT[l16][kk * 32 + quad * 8];
    h8 b0 = *(const h8*)&Wh[(wv * 2 + 0) * 16 + l16][kk * 32 + quad * 8];
    h8 b1 = *(const h8*)&Wh[(wv * 2 + 1) * 16 + l16][kk * 32 + quad * 8];
    acc[0] = MFMA16(a, b0, acc[0]);
    acc[1] = MFMA16(a, b1, acc[1]);
  }

#pragma unroll
  for (int ot = 0; ot < 2; ++ot) {     // store y + residual, gather GN stats
    const int o = (wv * 2 + ot) * 16 + l16;
    const int g = wv * 2 + ot;         // group index (16 ch/group)
    size_t addr = ((size_t)b * CC + o) * NN + n0 + quad * 4;
    float4 xv = *(const float4*)&x[addr];
    f4 a = acc[ot];
    float4 yy;
    yy.x = a[0] + xv.x; yy.y = a[1] + xv.y;
    yy.z = a[2] + xv.z; yy.w = a[3] + xv.w;
    *(float4*)&y[addr] = yy;
    float s = yy.x + yy.y + yy.z + yy.w;
    float sq = yy.x * yy.x + yy.y * yy.y + yy.z * yy.z + yy.w * yy.w;
#pragma unroll
    for (int off = 1; off < 64; off <<= 1) {
      s += __shfl_xor(s, off);
      sq += __shfl_xor(sq, off);
    }
    if (lane == 0) {
      atomicAdd(&stats[(b * 8 + g) * 2 + 0], s);
      atomicAdd(&stats[(b * 8 + g) * 2 + 1], sq);
    }
  }
}

// ---------------- kernel D: GroupNorm finalize + affine + SiLU ----------------
__global__ __launch_bounds__(256) void gn_silu(
    const float* __restrict__ y, const float* __restrict__ stats,
    const float* __restrict__ gamma, const float* __restrict__ beta,
    float* __restrict__ out) {
  const int tid = blockIdx.x * 256 + threadIdx.x;
  const int i4 = tid * 4;
  const int c = (i4 >> 12) & (CC - 1);
  const int b = i4 >> 19;
  const int g = c >> 4;
  const float inv = 1.f / 65536.f;
  float sum = stats[(b * 8 + g) * 2 + 0];
  float sq  = stats[(b * 8 + g) * 2 + 1];
  float mean = sum * inv;
  float var = sq * inv - mean * mean;
  float rs = rsqrtf(var + 1e-5f);
  float ga = gamma[c], be = beta[c];
  float4 v4 = *(const float4*)&y[i4];
  float4 r;
  float o;
  o = (v4.x - mean) * rs * ga + be; r.x = o / (1.f + __expf(-o));
  o = (v4.y - mean) * rs * ga + be; r.y = o / (1.f + __expf(-o));
  o = (v4.z - mean) * rs * ga + be; r.z = o / (1.f + __expf(-o));
  o = (v4.w - mean) * rs * ga + be; r.w = o / (1.f + __expf(-o));
  *(float4*)&out[i4] = r;
}

extern "C" void kernel_launch(void* const* d_in, const int* in_sizes, int n_in,
                              void* d_out, int out_size, void* d_ws, size_t ws_size,
                              hipStream_t stream) {
  const float* x     = (const float*)d_in[0];
  const float* Wq    = (const float*)d_in[1];
  const float* Wk    = (const float*)d_in[2];
  const float* Wv    = (const float*)d_in[3];
  const float* Wo    = (const float*)d_in[4];
  const float* gamma = (const float*)d_in[5];
  const float* beta  = (const float*)d_in[6];
  float* out = (float*)d_out;
  float* ws  = (float*)d_ws;

  // ws layout (~30.3 MB of the 256 MB workspace):
  // [0,16M):     Op partials bf16 [8 splits][b][n][c]       = 16 MB
  // [16M,18M):   qT fp16   [18M,20M): kT fp16   [20M,22M): vB bf16
  // [22M,26M):   y fp32 (4 MB)
  // [26M,...):   Lg (256 KB) + stats (128 B)
  const size_t M = (size_t)NB * CC * NN;  // 1,048,576 elems
  ushort* Op = (ushort*)ws;               // NSPLIT*M ushorts = 16 MB
  ushort* qT = (ushort*)ws + (size_t)NSPLIT * M;
  ushort* kT = qT + M;
  ushort* vB = kT + M;
  float* y = (float*)(vB + M);
  float* Lg = y + M;
  float* stats = Lg + (size_t)NSPLIT * NB * NN;

  qkv_mm<<<dim3(NN / 32, NB, 3), 256, 0, stream>>>(x, Wq, Wk, Wv, qT, kT, vB, stats);
  attn_split<<<dim3(NN / 128, NSPLIT, NB), 256, 0, stream>>>(qT, kT, vB, Op, Lg);
  proj_mm<<<dim3(NN / 16, NB), 256, 0, stream>>>(x, Wo, Op, Lg, y, stats);
  gn_silu<<<dim3((int)(M / 1024)), 256, 0, stream>>>(y, stats, gamma, beta, out);
}

// Round 10
// 137.974 us; speedup vs baseline: 1.3252x; 1.3252x over previous
//
#include <hip/hip_runtime.h>

#define CC 128
#define NN 4096
#define NB 2
#define NSPLIT 8
#define TK 64
#define ITERS 8    // 512 keys per split / TK

typedef unsigned short ushort;
typedef unsigned int uint;
typedef __attribute__((ext_vector_type(8))) _Float16 h8;  // 8 f16 (4 VGPRs)
typedef __attribute__((ext_vector_type(8))) short s8;     // 8 bf16 (4 VGPRs)
typedef __attribute__((ext_vector_type(4))) float f4;     // 4 fp32 acc
#define MFMA16(a, b, c) __builtin_amdgcn_mfma_f32_16x16x32_f16(a, b, c, 0, 0, 0)
#define MFMAB(a, b, c)  __builtin_amdgcn_mfma_f32_16x16x32_bf16(a, b, c, 0, 0, 0)

__device__ __forceinline__ ushort f2h(float f) {
  _Float16 h = (_Float16)f;
  return *(ushort*)&h;
}
__device__ __forceinline__ ushort f2bf(float f) {
  uint u = __float_as_uint(f);
  u += 0x7fffu + ((u >> 16) & 1u);   // round-to-nearest-even
  return (ushort)(u >> 16);
}
__device__ __forceinline__ float bf2f(ushort u) {
  return __uint_as_float((uint)u << 16);
}

// ---------------- kernel A: q/k/v projections, SPLIT BY WHICH (R20, verified) --------
__global__ __launch_bounds__(256) void qkv_mm(
    const float* __restrict__ x, const float* __restrict__ Wq,
    const float* __restrict__ Wk, const float* __restrict__ Wv,
    ushort* __restrict__ qT, ushort* __restrict__ kT, ushort* __restrict__ vB,
    float* __restrict__ stats) {
  __shared__ ushort Wh[CC][136];     // fp16 W, +8 pad (2-way banks = free)
  __shared__ ushort xs[32][136];     // fp16 x^T tile [n][c]
  const int t = threadIdx.x;
  const int n0 = blockIdx.x * 32;
  const int b = blockIdx.y;
  const int which = blockIdx.z;

  if (blockIdx.x == 0 && b == 0 && which == 0 && t < 32) stats[t] = 0.f;

  {  // stage x tile with 4x4 register transpose: one slot per thread (verified)
    int c0 = (t & 31) * 4;
    int n4 = (t >> 5) * 4;
    float4 r0 = *(const float4*)&x[((size_t)b * CC + c0 + 0) * NN + n0 + n4];
    float4 r1 = *(const float4*)&x[((size_t)b * CC + c0 + 1) * NN + n0 + n4];
    float4 r2 = *(const float4*)&x[((size_t)b * CC + c0 + 2) * NN + n0 + n4];
    float4 r3 = *(const float4*)&x[((size_t)b * CC + c0 + 3) * NN + n0 + n4];
    ushort4 w0, w1, w2, w3;
    w0.x = f2h(r0.x); w0.y = f2h(r1.x); w0.z = f2h(r2.x); w0.w = f2h(r3.x);
    w1.x = f2h(r0.y); w1.y = f2h(r1.y); w1.z = f2h(r2.y); w1.w = f2h(r3.y);
    w2.x = f2h(r0.z); w2.y = f2h(r1.z); w2.z = f2h(r2.z); w2.w = f2h(r3.z);
    w3.x = f2h(r0.w); w3.y = f2h(r1.w); w3.z = f2h(r2.w); w3.w = f2h(r3.w);
    *(ushort4*)&xs[n4 + 0][c0] = w0;
    *(ushort4*)&xs[n4 + 1][c0] = w1;
    *(ushort4*)&xs[n4 + 2][c0] = w2;
    *(ushort4*)&xs[n4 + 3][c0] = w3;
  }

  {  // stage this block's W: fp32 -> fp16, coalesced (verified body)
    const float* W = (which == 0) ? Wq : (which == 1) ? Wk : Wv;
#pragma unroll
    for (int i = 0; i < 16; ++i) {
      int slot = t + 256 * i;
      int o = slot >> 5, c4 = (slot & 31) * 4;
      float4 w4 = *(const float4*)&W[o * CC + c4];
      ushort4 p; p.x = f2h(w4.x); p.y = f2h(w4.y); p.z = f2h(w4.z); p.w = f2h(w4.w);
      *(ushort4*)&Wh[o][c4] = p;
    }
  }
  __syncthreads();                     // xs + Wh ready; no more barriers

  const int wv = t >> 6, lane = t & 63;
  const int quad = lane >> 4, l16 = lane & 15;

  if (which < 2) {                     // q,k: D[o][n]  (verified R17 body)
    ushort* out = which ? kT : qT;
    f4 acc[2][2];
#pragma unroll
    for (int ot = 0; ot < 2; ++ot)
#pragma unroll
      for (int nt = 0; nt < 2; ++nt) acc[ot][nt] = (f4){0.f, 0.f, 0.f, 0.f};
#pragma unroll
    for (int kk = 0; kk < 4; ++kk) {
      h8 a0 = *(const h8*)&Wh[(wv * 2 + 0) * 16 + l16][kk * 32 + quad * 8];
      h8 a1 = *(const h8*)&Wh[(wv * 2 + 1) * 16 + l16][kk * 32 + quad * 8];
#pragma unroll
      for (int nt = 0; nt < 2; ++nt) {
        h8 bb = *(const h8*)&xs[nt * 16 + l16][kk * 32 + quad * 8];
        acc[0][nt] = MFMA16(a0, bb, acc[0][nt]);
        acc[1][nt] = MFMA16(a1, bb, acc[1][nt]);
      }
    }
#pragma unroll
    for (int ot = 0; ot < 2; ++ot)
#pragma unroll
      for (int nt = 0; nt < 2; ++nt) {
        f4 a = acc[ot][nt];
        ushort4 p; p.x = f2h(a[0]); p.y = f2h(a[1]); p.z = f2h(a[2]); p.w = f2h(a[3]);
        *(ushort4*)&out[((size_t)b * NN + n0 + nt * 16 + l16) * CC +
                        (wv * 2 + ot) * 16 + quad * 4] = p;
      }
  } else {                             // v: D[n][c]  (verified R17 body)
    f4 acc[2][2];
#pragma unroll
    for (int ci = 0; ci < 2; ++ci)
#pragma unroll
      for (int nt = 0; nt < 2; ++nt) acc[ci][nt] = (f4){0.f, 0.f, 0.f, 0.f};
#pragma unroll
    for (int kk = 0; kk < 4; ++kk) {
      h8 a0 = *(const h8*)&xs[0 * 16 + l16][kk * 32 + quad * 8];
      h8 a1 = *(const h8*)&xs[1 * 16 + l16][kk * 32 + quad * 8];
      h8 b0 = *(const h8*)&Wh[(wv * 2 + 0) * 16 + l16][kk * 32 + quad * 8];
      h8 b1 = *(const h8*)&Wh[(wv * 2 + 1) * 16 + l16][kk * 32 + quad * 8];
      acc[0][0] = MFMA16(a0, b0, acc[0][0]);
      acc[0][1] = MFMA16(a1, b0, acc[0][1]);
      acc[1][0] = MFMA16(a0, b1, acc[1][0]);
      acc[1][1] = MFMA16(a1, b1, acc[1][1]);
    }
#pragma unroll
    for (int ci = 0; ci < 2; ++ci)
#pragma unroll
      for (int nt = 0; nt < 2; ++nt) {
        f4 a = acc[ci][nt];
        ushort4 p; p.x = f2bf(a[0]); p.y = f2bf(a[1]); p.z = f2bf(a[2]); p.w = f2bf(a[3]);
        *(ushort4*)&vB[((size_t)b * CC + (wv * 2 + ci) * 16 + l16) * NN +
                       n0 + nt * 16 + quad * 4] = p;
      }
  }
}

// ---------------- kernel B: 8-way split-K flash (R17/R20, verified) ----------------
__global__ __launch_bounds__(256) void attn_split(
    const ushort* __restrict__ qTg, const ushort* __restrict__ kTg,
    const ushort* __restrict__ vBg, ushort* __restrict__ Op,
    float* __restrict__ Lg) {
  __shared__ ushort ksT[TK][136];      // [m][c] fp16, 17 KB
  __shared__ ushort vs[CC][72];        // [c][m] bf16, 18 KB
  __shared__ ushort psb[4][32][72];    // per-wave P [q][m] bf16, 18 KB

  const int t = threadIdx.x;
  const int b = blockIdx.z;
  const int split = blockIdx.y;
  const int n0 = blockIdx.x * 128;
  const int wv = t >> 6;
  const int lane = t & 63;
  const int quad = lane >> 4;
  const int l16 = lane & 15;
  const int nw = n0 + wv * 32;
  const int m00 = split * (NN / NSPLIT);

  const int krow = t >> 4, kcol = (t & 15) * 8;
  const int vrow = t >> 3, vcol = (t & 7) * 8;
  const ushort* kbp = kTg + ((size_t)b * NN + m00 + krow) * CC + kcol;
  const ushort* vbp = vBg + ((size_t)b * CC + vrow) * NN + m00 + vcol;

  const size_t qb0 = ((size_t)b * NN + nw + l16) * CC + quad * 8;
  const size_t qb1 = qb0 + (size_t)16 * CC;
  h8 aq[2][4];
#pragma unroll
  for (int kk = 0; kk < 4; ++kk) {
    aq[0][kk] = *(const h8*)&qTg[qb0 + kk * 32];
    aq[1][kk] = *(const h8*)&qTg[qb1 + kk * 32];
  }

  int4 k0 = *(const int4*)&kbp[0];
  int4 k1 = *(const int4*)&kbp[16 * CC];
  int4 k2 = *(const int4*)&kbp[32 * CC];
  int4 k3 = *(const int4*)&kbp[48 * CC];
  int4 v0 = *(const int4*)&vbp[0];
  int4 v1 = *(const int4*)&vbp[(size_t)32 * NN];
  int4 v2 = *(const int4*)&vbp[(size_t)64 * NN];
  int4 v3 = *(const int4*)&vbp[(size_t)96 * NN];

  s8 ones;
#pragma unroll
  for (int i = 0; i < 8; ++i) ones[i] = (short)0x3F80;  // bf16 1.0

  f4 o[2][8];
#pragma unroll
  for (int j = 0; j < 2; ++j)
#pragma unroll
    for (int ct = 0; ct < 8; ++ct) o[j][ct] = (f4){0.f, 0.f, 0.f, 0.f};
  f4 oL[2];
  oL[0] = (f4){0.f, 0.f, 0.f, 0.f};
  oL[1] = (f4){0.f, 0.f, 0.f, 0.f};

  for (int kt = 0; kt < ITERS; ++kt) {
    *(int4*)&ksT[krow][kcol]      = k0;
    *(int4*)&ksT[krow + 16][kcol] = k1;
    *(int4*)&ksT[krow + 32][kcol] = k2;
    *(int4*)&ksT[krow + 48][kcol] = k3;
    *(int4*)&vs[vrow][vcol]       = v0;
    *(int4*)&vs[vrow + 32][vcol]  = v1;
    *(int4*)&vs[vrow + 64][vcol]  = v2;
    *(int4*)&vs[vrow + 96][vcol]  = v3;
    __syncthreads();                   // K,V ready

    {  // prefetch next tile (drains over compute)
      int ktn = (kt + 1 < ITERS) ? kt + 1 : kt;
      const ushort* kp = kbp + (size_t)ktn * TK * CC;
      const ushort* vp = vbp + (size_t)ktn * TK;
      k0 = *(const int4*)&kp[0];
      k1 = *(const int4*)&kp[16 * CC];
      k2 = *(const int4*)&kp[32 * CC];
      k3 = *(const int4*)&kp[48 * CC];
      v0 = *(const int4*)&vp[0];
      v1 = *(const int4*)&vp[(size_t)32 * NN];
      v2 = *(const int4*)&vp[(size_t)64 * NN];
      v3 = *(const int4*)&vp[(size_t)96 * NN];
    }

    // scores TRANSPOSED: D = S^T[m][q]; A=K-frag (LDS, shared across j), B=Q.
    f4 s[2][4];
#pragma unroll
    for (int j = 0; j < 2; ++j)
#pragma unroll
      for (int mt = 0; mt < 4; ++mt) s[j][mt] = (f4){0.f, 0.f, 0.f, 0.f};
#pragma unroll
    for (int kk = 0; kk < 4; ++kk) {
      h8 b0 = *(const h8*)&ksT[ 0 + l16][kk * 32 + quad * 8];
      h8 b1 = *(const h8*)&ksT[16 + l16][kk * 32 + quad * 8];
      h8 b2 = *(const h8*)&ksT[32 + l16][kk * 32 + quad * 8];
      h8 b3 = *(const h8*)&ksT[48 + l16][kk * 32 + quad * 8];
#pragma unroll
      for (int j = 0; j < 2; ++j) {
        s[j][0] = MFMA16(b0, aq[j][kk], s[j][0]);
        s[j][1] = MFMA16(b1, aq[j][kk], s[j][1]);
        s[j][2] = MFMA16(b2, aq[j][kk], s[j][2]);
        s[j][3] = MFMA16(b3, aq[j][kk], s[j][3]);
      }
    }

    // max-free softmax: exp + packed b64 psb stores (8 stores for 32 q-rows)
#pragma unroll
    for (int j = 0; j < 2; ++j)
#pragma unroll
      for (int mt = 0; mt < 4; ++mt) {
        ushort4 pk;
        pk.x = f2bf(__expf(s[j][mt][0]));
        pk.y = f2bf(__expf(s[j][mt][1]));
        pk.z = f2bf(__expf(s[j][mt][2]));
        pk.w = f2bf(__expf(s[j][mt][3]));
        *(ushort4*)&psb[wv][j * 16 + l16][mt * 16 + quad * 4] = pk;
      }
    // same-wave DS is in-order: psb writes visible to reads below

    // PV (bf16): V-frags shared across both q-subtiles
#pragma unroll
    for (int mk = 0; mk < 2; ++mk) {
      s8 bp0 = *(const s8*)&psb[wv][ 0 + l16][mk * 32 + quad * 8];
      s8 bp1 = *(const s8*)&psb[wv][16 + l16][mk * 32 + quad * 8];
#pragma unroll
      for (int ct = 0; ct < 8; ++ct) {
        s8 a = *(const s8*)&vs[ct * 16 + l16][mk * 32 + quad * 8];
        o[0][ct] = MFMAB(a, bp0, o[0][ct]);
        o[1][ct] = MFMAB(a, bp1, o[1][ct]);
      }
      oL[0] = MFMAB(ones, bp0, oL[0]);
      oL[1] = MFMAB(ones, bp1, oL[1]);
    }
    __syncthreads();                   // all waves done reading ksT/vs
  }

  // epilogue: bf16 O partial [split*NB+b][n][c], packed 8B stores, both subtiles
#pragma unroll
  for (int j = 0; j < 2; ++j) {
    if (quad == 0)
      Lg[((size_t)(split * NB + b)) * NN + nw + j * 16 + l16] = oL[j][0];
    size_t nb_ = ((size_t)(split * NB + b) * NN + nw + j * 16 + l16) * CC + quad * 4;
    ushort4 p;
#pragma unroll
    for (int ct = 0; ct < 8; ++ct) {
      f4 a = o[j][ct];
      p.x = f2bf(a[0]); p.y = f2bf(a[1]); p.z = f2bf(a[2]); p.w = f2bf(a[3]);
      *(ushort4*)&Op[nb_ + ct * 16] = p;
    }
  }
}

// ---------------- kernel C: combine 8 splits + Wo projection + residual + GN stats ----
// R23: 32-n tile (R20 structure) with the combine loop FIXED to 4 iterations
// (32 rows x 32 c4-slots = 1024 slots = 4 x 256 threads). The previous 16-iter
// loop issued 4x-redundant Op reads (n=slot>>5 ran to 127) and wrote hT out of
// bounds in LDS (benign only because MFMA reads rows 0-31). -48 MB issued loads.
__global__ __launch_bounds__(256) void proj_mm(
    const float* __restrict__ x, const float* __restrict__ Wo,
    const ushort* __restrict__ Op, const float* __restrict__ Lg,
    float* __restrict__ y, float* __restrict__ stats) {
  __shared__ ushort Wh[CC][136];
  __shared__ ushort hT[32][136];
  __shared__ float Linv[32];
  const int t = threadIdx.x;
  const int n0 = blockIdx.x * 32;
  const int b = blockIdx.y;

#pragma unroll
  for (int i = 0; i < 16; ++i) {       // stage Wo -> fp16 (128 rows: 16 iters correct)
    int slot = t + 256 * i;
    int o = slot >> 5, c4 = (slot & 31) * 4;
    float4 w4 = *(const float4*)&Wo[o * CC + c4];
    ushort4 p; p.x = f2h(w4.x); p.y = f2h(w4.y); p.z = f2h(w4.z); p.w = f2h(w4.w);
    *(ushort4*)&Wh[o][c4] = p;
  }
  if (t < 32) {
    float l = 0.f;
#pragma unroll
    for (int s = 0; s < NSPLIT; ++s)
      l += Lg[(size_t)(s * NB + b) * NN + n0 + t];
    Linv[t] = 1.f / l;
  }
  __syncthreads();

#pragma unroll
  for (int i = 0; i < 4; ++i) {        // combine 8 bf16 splits -> h^T fp16 (32 rows)
    int slot = t + 256 * i;
    int n = slot >> 5, c4 = (slot & 31) * 4;
    size_t base = ((size_t)(n0 + n)) * CC + c4;
    float a0 = 0.f, a1 = 0.f, a2 = 0.f, a3 = 0.f;
#pragma unroll
    for (int s = 0; s < NSPLIT; ++s) {
      ushort4 u = *(const ushort4*)&Op[(size_t)(s * NB + b) * NN * CC + base];
      a0 += bf2f(u.x); a1 += bf2f(u.y); a2 += bf2f(u.z); a3 += bf2f(u.w);
    }
    float li = Linv[n];
    ushort4 p;
    p.x = f2h(a0 * li); p.y = f2h(a1 * li);
    p.z = f2h(a2 * li); p.w = f2h(a3 * li);
    *(ushort4*)&hT[n][c4] = p;
  }
  __syncthreads();

  const int wv = t >> 6, lane = t & 63;
  const int quad = lane >> 4, l16 = lane & 15;

  f4 acc[2][2];                        // [nt][ot]
#pragma unroll
  for (int nt = 0; nt < 2; ++nt)
#pragma unroll
    for (int ot = 0; ot < 2; ++ot) acc[nt][ot] = (f4){0.f, 0.f, 0.f, 0.f};
#pragma unroll
  for (int kk = 0; kk < 4; ++kk) {
    h8 a0 = *(const h8*)&hT[0 * 16 + l16][kk * 32 + quad * 8];
    h8 a1 = *(const h8*)&hT[1 * 16 + l16][kk * 32 + quad * 8];
    h8 b0 = *(const h8*)&Wh[(wv * 2 + 0) * 16 + l16][kk * 32 + quad * 8];
    h8 b1 = *(const h8*)&Wh[(wv * 2 + 1) * 16 + l16][kk * 32 + quad * 8];
    acc[0][0] = MFMA16(a0, b0, acc[0][0]);
    acc[0][1] = MFMA16(a0, b1, acc[0][1]);
    acc[1][0] = MFMA16(a1, b0, acc[1][0]);
    acc[1][1] = MFMA16(a1, b1, acc[1][1]);
  }

#pragma unroll
  for (int ot = 0; ot < 2; ++ot) {     // store y + residual, gather GN stats
    const int o = (wv * 2 + ot) * 16 + l16;
    const int g = wv * 2 + ot;         // group index (16 ch/group)
    float s = 0.f, sq = 0.f;
#pragma unroll
    for (int nt = 0; nt < 2; ++nt) {
      size_t addr = ((size_t)b * CC + o) * NN + n0 + nt * 16 + quad * 4;
      float4 xv = *(const float4*)&x[addr];
      f4 a = acc[nt][ot];
      float4 yy;
      yy.x = a[0] + xv.x; yy.y = a[1] + xv.y;
      yy.z = a[2] + xv.z; yy.w = a[3] + xv.w;
      *(float4*)&y[addr] = yy;
      s += yy.x + yy.y + yy.z + yy.w;
      sq += yy.x * yy.x + yy.y * yy.y + yy.z * yy.z + yy.w * yy.w;
    }
#pragma unroll
    for (int off = 1; off < 64; off <<= 1) {
      s += __shfl_xor(s, off);
      sq += __shfl_xor(sq, off);
    }
    if (lane == 0) {
      atomicAdd(&stats[(b * 8 + g) * 2 + 0], s);
      atomicAdd(&stats[(b * 8 + g) * 2 + 1], sq);
    }
  }
}

// ---------------- kernel D: GroupNorm finalize + affine + SiLU ----------------
__global__ __launch_bounds__(256) void gn_silu(
    const float* __restrict__ y, const float* __restrict__ stats,
    const float* __restrict__ gamma, const float* __restrict__ beta,
    float* __restrict__ out) {
  const int tid = blockIdx.x * 256 + threadIdx.x;
  const int i4 = tid * 4;
  const int c = (i4 >> 12) & (CC - 1);
  const int b = i4 >> 19;
  const int g = c >> 4;
  const float inv = 1.f / 65536.f;
  float sum = stats[(b * 8 + g) * 2 + 0];
  float sq  = stats[(b * 8 + g) * 2 + 1];
  float mean = sum * inv;
  float var = sq * inv - mean * mean;
  float rs = rsqrtf(var + 1e-5f);
  float ga = gamma[c], be = beta[c];
  float4 v4 = *(const float4*)&y[i4];
  float4 r;
  float o;
  o = (v4.x - mean) * rs * ga + be; r.x = o / (1.f + __expf(-o));
  o = (v4.y - mean) * rs * ga + be; r.y = o / (1.f + __expf(-o));
  o = (v4.z - mean) * rs * ga + be; r.z = o / (1.f + __expf(-o));
  o = (v4.w - mean) * rs * ga + be; r.w = o / (1.f + __expf(-o));
  *(float4*)&out[i4] = r;
}

extern "C" void kernel_launch(void* const* d_in, const int* in_sizes, int n_in,
                              void* d_out, int out_size, void* d_ws, size_t ws_size,
                              hipStream_t stream) {
  const float* x     = (const float*)d_in[0];
  const float* Wq    = (const float*)d_in[1];
  const float* Wk    = (const float*)d_in[2];
  const float* Wv    = (const float*)d_in[3];
  const float* Wo    = (const float*)d_in[4];
  const float* gamma = (const float*)d_in[5];
  const float* beta  = (const float*)d_in[6];
  float* out = (float*)d_out;
  float* ws  = (float*)d_ws;

  // ws layout (~30.3 MB of the 256 MB workspace):
  // [0,16M):     Op partials bf16 [8 splits][b][n][c]       = 16 MB
  // [16M,18M):   qT fp16   [18M,20M): kT fp16   [20M,22M): vB bf16
  // [22M,26M):   y fp32 (4 MB)
  // [26M,...):   Lg (256 KB) + stats (128 B)
  const size_t M = (size_t)NB * CC * NN;  // 1,048,576 elems
  ushort* Op = (ushort*)ws;               // NSPLIT*M ushorts = 16 MB
  ushort* qT = (ushort*)ws + (size_t)NSPLIT * M;
  ushort* kT = qT + M;
  ushort* vB = kT + M;
  float* y = (float*)(vB + M);
  float* Lg = y + M;
  float* stats = Lg + (size_t)NSPLIT * NB * NN;

  qkv_mm<<<dim3(NN / 32, NB, 3), 256, 0, stream>>>(x, Wq, Wk, Wv, qT, kT, vB, stats);
  attn_split<<<dim3(NN / 128, NSPLIT, NB), 256, 0, stream>>>(qT, kT, vB, Op, Lg);
  proj_mm<<<dim3(NN / 32, NB), 256, 0, stream>>>(x, Wo, Op, Lg, y, stats);
  gn_silu<<<dim3((int)(M / 1024)), 256, 0, stream>>>(y, stats, gamma, beta, out);
}

// Round 11
// 136.577 us; speedup vs baseline: 1.3388x; 1.0102x over previous
//
#include <hip/hip_runtime.h>

#define CC 128
#define NN 4096
#define NB 2
#define NSPLIT 8
#define TK 64
#define ITERS 8    // 512 keys per split / TK

typedef unsigned short ushort;
typedef unsigned int uint;
typedef __attribute__((ext_vector_type(8))) _Float16 h8;  // 8 f16 (4 VGPRs)
typedef __attribute__((ext_vector_type(8))) short s8;     // 8 bf16 (4 VGPRs)
typedef __attribute__((ext_vector_type(4))) float f4;     // 4 fp32 acc
#define MFMA16(a, b, c) __builtin_amdgcn_mfma_f32_16x16x32_f16(a, b, c, 0, 0, 0)
#define MFMAB(a, b, c)  __builtin_amdgcn_mfma_f32_16x16x32_bf16(a, b, c, 0, 0, 0)

__device__ __forceinline__ ushort f2h(float f) {
  _Float16 h = (_Float16)f;
  return *(ushort*)&h;
}
__device__ __forceinline__ ushort f2bf(float f) {
  uint u = __float_as_uint(f);
  u += 0x7fffu + ((u >> 16) & 1u);   // round-to-nearest-even
  return (ushort)(u >> 16);
}
__device__ __forceinline__ float bf2f(ushort u) {
  return __uint_as_float((uint)u << 16);
}
// Pack 2 fp32 -> 2 bf16 (RNE) in ONE VALU inst. No builtin on gfx950 (m240) —
// inline asm. D[15:0]=bf16(a), D[31:16]=bf16(b): little-endian ushort order (a,b).
__device__ __forceinline__ uint cvt_pk_bf16(float a, float b) {
  uint r;
  asm("v_cvt_pk_bf16_f32 %0, %1, %2" : "=v"(r) : "v"(a), "v"(b));
  return r;
}

// ---------------- kernel A: q/k/v projections, SPLIT BY WHICH (R20, verified) --------
__global__ __launch_bounds__(256) void qkv_mm(
    const float* __restrict__ x, const float* __restrict__ Wq,
    const float* __restrict__ Wk, const float* __restrict__ Wv,
    ushort* __restrict__ qT, ushort* __restrict__ kT, ushort* __restrict__ vB,
    float* __restrict__ stats) {
  __shared__ ushort Wh[CC][136];     // fp16 W, +8 pad (2-way banks = free)
  __shared__ ushort xs[32][136];     // fp16 x^T tile [n][c]
  const int t = threadIdx.x;
  const int n0 = blockIdx.x * 32;
  const int b = blockIdx.y;
  const int which = blockIdx.z;

  if (blockIdx.x == 0 && b == 0 && which == 0 && t < 32) stats[t] = 0.f;

  {  // stage x tile with 4x4 register transpose: one slot per thread (verified)
    int c0 = (t & 31) * 4;
    int n4 = (t >> 5) * 4;
    float4 r0 = *(const float4*)&x[((size_t)b * CC + c0 + 0) * NN + n0 + n4];
    float4 r1 = *(const float4*)&x[((size_t)b * CC + c0 + 1) * NN + n0 + n4];
    float4 r2 = *(const float4*)&x[((size_t)b * CC + c0 + 2) * NN + n0 + n4];
    float4 r3 = *(const float4*)&x[((size_t)b * CC + c0 + 3) * NN + n0 + n4];
    ushort4 w0, w1, w2, w3;
    w0.x = f2h(r0.x); w0.y = f2h(r1.x); w0.z = f2h(r2.x); w0.w = f2h(r3.x);
    w1.x = f2h(r0.y); w1.y = f2h(r1.y); w1.z = f2h(r2.y); w1.w = f2h(r3.y);
    w2.x = f2h(r0.z); w2.y = f2h(r1.z); w2.z = f2h(r2.z); w2.w = f2h(r3.z);
    w3.x = f2h(r0.w); w3.y = f2h(r1.w); w3.z = f2h(r2.w); w3.w = f2h(r3.w);
    *(ushort4*)&xs[n4 + 0][c0] = w0;
    *(ushort4*)&xs[n4 + 1][c0] = w1;
    *(ushort4*)&xs[n4 + 2][c0] = w2;
    *(ushort4*)&xs[n4 + 3][c0] = w3;
  }

  {  // stage this block's W: fp32 -> fp16, coalesced (verified body)
    const float* W = (which == 0) ? Wq : (which == 1) ? Wk : Wv;
#pragma unroll
    for (int i = 0; i < 16; ++i) {
      int slot = t + 256 * i;
      int o = slot >> 5, c4 = (slot & 31) * 4;
      float4 w4 = *(const float4*)&W[o * CC + c4];
      ushort4 p; p.x = f2h(w4.x); p.y = f2h(w4.y); p.z = f2h(w4.z); p.w = f2h(w4.w);
      *(ushort4*)&Wh[o][c4] = p;
    }
  }
  __syncthreads();                     // xs + Wh ready; no more barriers

  const int wv = t >> 6, lane = t & 63;
  const int quad = lane >> 4, l16 = lane & 15;

  if (which < 2) {                     // q,k: D[o][n]  (verified R17 body)
    ushort* out = which ? kT : qT;
    f4 acc[2][2];
#pragma unroll
    for (int ot = 0; ot < 2; ++ot)
#pragma unroll
      for (int nt = 0; nt < 2; ++nt) acc[ot][nt] = (f4){0.f, 0.f, 0.f, 0.f};
#pragma unroll
    for (int kk = 0; kk < 4; ++kk) {
      h8 a0 = *(const h8*)&Wh[(wv * 2 + 0) * 16 + l16][kk * 32 + quad * 8];
      h8 a1 = *(const h8*)&Wh[(wv * 2 + 1) * 16 + l16][kk * 32 + quad * 8];
#pragma unroll
      for (int nt = 0; nt < 2; ++nt) {
        h8 bb = *(const h8*)&xs[nt * 16 + l16][kk * 32 + quad * 8];
        acc[0][nt] = MFMA16(a0, bb, acc[0][nt]);
        acc[1][nt] = MFMA16(a1, bb, acc[1][nt]);
      }
    }
#pragma unroll
    for (int ot = 0; ot < 2; ++ot)
#pragma unroll
      for (int nt = 0; nt < 2; ++nt) {
        f4 a = acc[ot][nt];
        ushort4 p; p.x = f2h(a[0]); p.y = f2h(a[1]); p.z = f2h(a[2]); p.w = f2h(a[3]);
        *(ushort4*)&out[((size_t)b * NN + n0 + nt * 16 + l16) * CC +
                        (wv * 2 + ot) * 16 + quad * 4] = p;
      }
  } else {                             // v: D[n][c]  (verified R17 body)
    f4 acc[2][2];
#pragma unroll
    for (int ci = 0; ci < 2; ++ci)
#pragma unroll
      for (int nt = 0; nt < 2; ++nt) acc[ci][nt] = (f4){0.f, 0.f, 0.f, 0.f};
#pragma unroll
    for (int kk = 0; kk < 4; ++kk) {
      h8 a0 = *(const h8*)&xs[0 * 16 + l16][kk * 32 + quad * 8];
      h8 a1 = *(const h8*)&xs[1 * 16 + l16][kk * 32 + quad * 8];
      h8 b0 = *(const h8*)&Wh[(wv * 2 + 0) * 16 + l16][kk * 32 + quad * 8];
      h8 b1 = *(const h8*)&Wh[(wv * 2 + 1) * 16 + l16][kk * 32 + quad * 8];
      acc[0][0] = MFMA16(a0, b0, acc[0][0]);
      acc[0][1] = MFMA16(a1, b0, acc[0][1]);
      acc[1][0] = MFMA16(a0, b1, acc[1][0]);
      acc[1][1] = MFMA16(a1, b1, acc[1][1]);
    }
#pragma unroll
    for (int ci = 0; ci < 2; ++ci)
#pragma unroll
      for (int nt = 0; nt < 2; ++nt) {
        f4 a = acc[ci][nt];
        ushort4 p; p.x = f2bf(a[0]); p.y = f2bf(a[1]); p.z = f2bf(a[2]); p.w = f2bf(a[3]);
        *(ushort4*)&vB[((size_t)b * CC + (wv * 2 + ci) * 16 + l16) * NN +
                       n0 + nt * 16 + quad * 4] = p;
      }
  }
}

// ---------------- kernel B: 8-way split-K flash (R17/R20 structure) ----------------
// R24: (1) P-pack via v_cvt_pk_bf16_f32 (16 inst vs ~96 scalar VALU per wave-iter;
// identical RNE bits); (2) s_setprio(1) around the MFMA clusters (T5 — 2 blocks/CU
// give the scheduler wave-phase diversity to arbitrate; +4-7% attn in learn_hip m191).
__global__ __launch_bounds__(256) void attn_split(
    const ushort* __restrict__ qTg, const ushort* __restrict__ kTg,
    const ushort* __restrict__ vBg, ushort* __restrict__ Op,
    float* __restrict__ Lg) {
  __shared__ ushort ksT[TK][136];      // [m][c] fp16, 17 KB
  __shared__ ushort vs[CC][72];        // [c][m] bf16, 18 KB
  __shared__ ushort psb[4][32][72];    // per-wave P [q][m] bf16, 18 KB

  const int t = threadIdx.x;
  const int b = blockIdx.z;
  const int split = blockIdx.y;
  const int n0 = blockIdx.x * 128;
  const int wv = t >> 6;
  const int lane = t & 63;
  const int quad = lane >> 4;
  const int l16 = lane & 15;
  const int nw = n0 + wv * 32;
  const int m00 = split * (NN / NSPLIT);

  const int krow = t >> 4, kcol = (t & 15) * 8;
  const int vrow = t >> 3, vcol = (t & 7) * 8;
  const ushort* kbp = kTg + ((size_t)b * NN + m00 + krow) * CC + kcol;
  const ushort* vbp = vBg + ((size_t)b * CC + vrow) * NN + m00 + vcol;

  const size_t qb0 = ((size_t)b * NN + nw + l16) * CC + quad * 8;
  const size_t qb1 = qb0 + (size_t)16 * CC;
  h8 aq[2][4];
#pragma unroll
  for (int kk = 0; kk < 4; ++kk) {
    aq[0][kk] = *(const h8*)&qTg[qb0 + kk * 32];
    aq[1][kk] = *(const h8*)&qTg[qb1 + kk * 32];
  }

  int4 k0 = *(const int4*)&kbp[0];
  int4 k1 = *(const int4*)&kbp[16 * CC];
  int4 k2 = *(const int4*)&kbp[32 * CC];
  int4 k3 = *(const int4*)&kbp[48 * CC];
  int4 v0 = *(const int4*)&vbp[0];
  int4 v1 = *(const int4*)&vbp[(size_t)32 * NN];
  int4 v2 = *(const int4*)&vbp[(size_t)64 * NN];
  int4 v3 = *(const int4*)&vbp[(size_t)96 * NN];

  s8 ones;
#pragma unroll
  for (int i = 0; i < 8; ++i) ones[i] = (short)0x3F80;  // bf16 1.0

  f4 o[2][8];
#pragma unroll
  for (int j = 0; j < 2; ++j)
#pragma unroll
    for (int ct = 0; ct < 8; ++ct) o[j][ct] = (f4){0.f, 0.f, 0.f, 0.f};
  f4 oL[2];
  oL[0] = (f4){0.f, 0.f, 0.f, 0.f};
  oL[1] = (f4){0.f, 0.f, 0.f, 0.f};

  for (int kt = 0; kt < ITERS; ++kt) {
    *(int4*)&ksT[krow][kcol]      = k0;
    *(int4*)&ksT[krow + 16][kcol] = k1;
    *(int4*)&ksT[krow + 32][kcol] = k2;
    *(int4*)&ksT[krow + 48][kcol] = k3;
    *(int4*)&vs[vrow][vcol]       = v0;
    *(int4*)&vs[vrow + 32][vcol]  = v1;
    *(int4*)&vs[vrow + 64][vcol]  = v2;
    *(int4*)&vs[vrow + 96][vcol]  = v3;
    __syncthreads();                   // K,V ready

    {  // prefetch next tile (drains over compute)
      int ktn = (kt + 1 < ITERS) ? kt + 1 : kt;
      const ushort* kp = kbp + (size_t)ktn * TK * CC;
      const ushort* vp = vbp + (size_t)ktn * TK;
      k0 = *(const int4*)&kp[0];
      k1 = *(const int4*)&kp[16 * CC];
      k2 = *(const int4*)&kp[32 * CC];
      k3 = *(const int4*)&kp[48 * CC];
      v0 = *(const int4*)&vp[0];
      v1 = *(const int4*)&vp[(size_t)32 * NN];
      v2 = *(const int4*)&vp[(size_t)64 * NN];
      v3 = *(const int4*)&vp[(size_t)96 * NN];
    }

    // scores TRANSPOSED: D = S^T[m][q]; A=K-frag (LDS, shared across j), B=Q.
    f4 s[2][4];
#pragma unroll
    for (int j = 0; j < 2; ++j)
#pragma unroll
      for (int mt = 0; mt < 4; ++mt) s[j][mt] = (f4){0.f, 0.f, 0.f, 0.f};
    __builtin_amdgcn_s_setprio(1);
#pragma unroll
    for (int kk = 0; kk < 4; ++kk) {
      h8 b0 = *(const h8*)&ksT[ 0 + l16][kk * 32 + quad * 8];
      h8 b1 = *(const h8*)&ksT[16 + l16][kk * 32 + quad * 8];
      h8 b2 = *(const h8*)&ksT[32 + l16][kk * 32 + quad * 8];
      h8 b3 = *(const h8*)&ksT[48 + l16][kk * 32 + quad * 8];
#pragma unroll
      for (int j = 0; j < 2; ++j) {
        s[j][0] = MFMA16(b0, aq[j][kk], s[j][0]);
        s[j][1] = MFMA16(b1, aq[j][kk], s[j][1]);
        s[j][2] = MFMA16(b2, aq[j][kk], s[j][2]);
        s[j][3] = MFMA16(b3, aq[j][kk], s[j][3]);
      }
    }
    __builtin_amdgcn_s_setprio(0);

    // max-free softmax: exp + ONE v_cvt_pk_bf16_f32 per bf16 pair (R24)
#pragma unroll
    for (int j = 0; j < 2; ++j)
#pragma unroll
      for (int mt = 0; mt < 4; ++mt) {
        uint2 pk;
        pk.x = cvt_pk_bf16(__expf(s[j][mt][0]), __expf(s[j][mt][1]));
        pk.y = cvt_pk_bf16(__expf(s[j][mt][2]), __expf(s[j][mt][3]));
        *(uint2*)&psb[wv][j * 16 + l16][mt * 16 + quad * 4] = pk;
      }
    // same-wave DS is in-order: psb writes visible to reads below

    // PV (bf16): V-frags shared across both q-subtiles
    __builtin_amdgcn_s_setprio(1);
#pragma unroll
    for (int mk = 0; mk < 2; ++mk) {
      s8 bp0 = *(const s8*)&psb[wv][ 0 + l16][mk * 32 + quad * 8];
      s8 bp1 = *(const s8*)&psb[wv][16 + l16][mk * 32 + quad * 8];
#pragma unroll
      for (int ct = 0; ct < 8; ++ct) {
        s8 a = *(const s8*)&vs[ct * 16 + l16][mk * 32 + quad * 8];
        o[0][ct] = MFMAB(a, bp0, o[0][ct]);
        o[1][ct] = MFMAB(a, bp1, o[1][ct]);
      }
      oL[0] = MFMAB(ones, bp0, oL[0]);
      oL[1] = MFMAB(ones, bp1, oL[1]);
    }
    __builtin_amdgcn_s_setprio(0);
    __syncthreads();                   // all waves done reading ksT/vs
  }

  // epilogue: bf16 O partial [split*NB+b][n][c], packed 8B stores, both subtiles
#pragma unroll
  for (int j = 0; j < 2; ++j) {
    if (quad == 0)
      Lg[((size_t)(split * NB + b)) * NN + nw + j * 16 + l16] = oL[j][0];
    size_t nb_ = ((size_t)(split * NB + b) * NN + nw + j * 16 + l16) * CC + quad * 4;
    ushort4 p;
#pragma unroll
    for (int ct = 0; ct < 8; ++ct) {
      f4 a = o[j][ct];
      p.x = f2bf(a[0]); p.y = f2bf(a[1]); p.z = f2bf(a[2]); p.w = f2bf(a[3]);
      *(ushort4*)&Op[nb_ + ct * 16] = p;
    }
  }
}

// ---------------- kernel C: combine 8 splits + Wo projection + residual + GN stats ----
// R23 structure (verified): combine loop = 4 iterations (exact cover, no OOB).
__global__ __launch_bounds__(256) void proj_mm(
    const float* __restrict__ x, const float* __restrict__ Wo,
    const ushort* __restrict__ Op, const float* __restrict__ Lg,
    float* __restrict__ y, float* __restrict__ stats) {
  __shared__ ushort Wh[CC][136];
  __shared__ ushort hT[32][136];
  __shared__ float Linv[32];
  const int t = threadIdx.x;
  const int n0 = blockIdx.x * 32;
  const int b = blockIdx.y;

#pragma unroll
  for (int i = 0; i < 16; ++i) {       // stage Wo -> fp16 (128 rows: 16 iters correct)
    int slot = t + 256 * i;
    int o = slot >> 5, c4 = (slot & 31) * 4;
    float4 w4 = *(const float4*)&Wo[o * CC + c4];
    ushort4 p; p.x = f2h(w4.x); p.y = f2h(w4.y); p.z = f2h(w4.z); p.w = f2h(w4.w);
    *(ushort4*)&Wh[o][c4] = p;
  }
  if (t < 32) {
    float l = 0.f;
#pragma unroll
    for (int s = 0; s < NSPLIT; ++s)
      l += Lg[(size_t)(s * NB + b) * NN + n0 + t];
    Linv[t] = 1.f / l;
  }
  __syncthreads();

#pragma unroll
  for (int i = 0; i < 4; ++i) {        // combine 8 bf16 splits -> h^T fp16 (32 rows)
    int slot = t + 256 * i;
    int n = slot >> 5, c4 = (slot & 31) * 4;
    size_t base = ((size_t)(n0 + n)) * CC + c4;
    float a0 = 0.f, a1 = 0.f, a2 = 0.f, a3 = 0.f;
#pragma unroll
    for (int s = 0; s < NSPLIT; ++s) {
      ushort4 u = *(const ushort4*)&Op[(size_t)(s * NB + b) * NN * CC + base];
      a0 += bf2f(u.x); a1 += bf2f(u.y); a2 += bf2f(u.z); a3 += bf2f(u.w);
    }
    float li = Linv[n];
    ushort4 p;
    p.x = f2h(a0 * li); p.y = f2h(a1 * li);
    p.z = f2h(a2 * li); p.w = f2h(a3 * li);
    *(ushort4*)&hT[n][c4] = p;
  }
  __syncthreads();

  const int wv = t >> 6, lane = t & 63;
  const int quad = lane >> 4, l16 = lane & 15;

  f4 acc[2][2];                        // [nt][ot]
#pragma unroll
  for (int nt = 0; nt < 2; ++nt)
#pragma unroll
    for (int ot = 0; ot < 2; ++ot) acc[nt][ot] = (f4){0.f, 0.f, 0.f, 0.f};
#pragma unroll
  for (int kk = 0; kk < 4; ++kk) {
    h8 a0 = *(const h8*)&hT[0 * 16 + l16][kk * 32 + quad * 8];
    h8 a1 = *(const h8*)&hT[1 * 16 + l16][kk * 32 + quad * 8];
    h8 b0 = *(const h8*)&Wh[(wv * 2 + 0) * 16 + l16][kk * 32 + quad * 8];
    h8 b1 = *(const h8*)&Wh[(wv * 2 + 1) * 16 + l16][kk * 32 + quad * 8];
    acc[0][0] = MFMA16(a0, b0, acc[0][0]);
    acc[0][1] = MFMA16(a0, b1, acc[0][1]);
    acc[1][0] = MFMA16(a1, b0, acc[1][0]);
    acc[1][1] = MFMA16(a1, b1, acc[1][1]);
  }

#pragma unroll
  for (int ot = 0; ot < 2; ++ot) {     // store y + residual, gather GN stats
    const int o = (wv * 2 + ot) * 16 + l16;
    const int g = wv * 2 + ot;         // group index (16 ch/group)
    float s = 0.f, sq = 0.f;
#pragma unroll
    for (int nt = 0; nt < 2; ++nt) {
      size_t addr = ((size_t)b * CC + o) * NN + n0 + nt * 16 + quad * 4;
      float4 xv = *(const float4*)&x[addr];
      f4 a = acc[nt][ot];
      float4 yy;
      yy.x = a[0] + xv.x; yy.y = a[1] + xv.y;
      yy.z = a[2] + xv.z; yy.w = a[3] + xv.w;
      *(float4*)&y[addr] = yy;
      s += yy.x + yy.y + yy.z + yy.w;
      sq += yy.x * yy.x + yy.y * yy.y + yy.z * yy.z + yy.w * yy.w;
    }
#pragma unroll
    for (int off = 1; off < 64; off <<= 1) {
      s += __shfl_xor(s, off);
      sq += __shfl_xor(sq, off);
    }
    if (lane == 0) {
      atomicAdd(&stats[(b * 8 + g) * 2 + 0], s);
      atomicAdd(&stats[(b * 8 + g) * 2 + 1], sq);
    }
  }
}

// ---------------- kernel D: GroupNorm finalize + affine + SiLU ----------------
__global__ __launch_bounds__(256) void gn_silu(
    const float* __restrict__ y, const float* __restrict__ stats,
    const float* __restrict__ gamma, const float* __restrict__ beta,
    float* __restrict__ out) {
  const int tid = blockIdx.x * 256 + threadIdx.x;
  const int i4 = tid * 4;
  const int c = (i4 >> 12) & (CC - 1);
  const int b = i4 >> 19;
  const int g = c >> 4;
  const float inv = 1.f / 65536.f;
  float sum = stats[(b * 8 + g) * 2 + 0];
  float sq  = stats[(b * 8 + g) * 2 + 1];
  float mean = sum * inv;
  float var = sq * inv - mean * mean;
  float rs = rsqrtf(var + 1e-5f);
  float ga = gamma[c], be = beta[c];
  float4 v4 = *(const float4*)&y[i4];
  float4 r;
  float o;
  o = (v4.x - mean) * rs * ga + be; r.x = o / (1.f + __expf(-o));
  o = (v4.y - mean) * rs * ga + be; r.y = o / (1.f + __expf(-o));
  o = (v4.z - mean) * rs * ga + be; r.z = o / (1.f + __expf(-o));
  o = (v4.w - mean) * rs * ga + be; r.w = o / (1.f + __expf(-o));
  *(float4*)&out[i4] = r;
}

extern "C" void kernel_launch(void* const* d_in, const int* in_sizes, int n_in,
                              void* d_out, int out_size, void* d_ws, size_t ws_size,
                              hipStream_t stream) {
  const float* x     = (const float*)d_in[0];
  const float* Wq    = (const float*)d_in[1];
  const float* Wk    = (const float*)d_in[2];
  const float* Wv    = (const float*)d_in[3];
  const float* Wo    = (const float*)d_in[4];
  const float* gamma = (const float*)d_in[5];
  const float* beta  = (const float*)d_in[6];
  float* out = (float*)d_out;
  float* ws  = (float*)d_ws;

  // ws layout (~30.3 MB of the 256 MB workspace):
  // [0,16M):     Op partials bf16 [8 splits][b][n][c]       = 16 MB
  // [16M,18M):   qT fp16   [18M,20M): kT fp16   [20M,22M): vB bf16
  // [22M,26M):   y fp32 (4 MB)
  // [26M,...):   Lg (256 KB) + stats (128 B)
  const size_t M = (size_t)NB * CC * NN;  // 1,048,576 elems
  ushort* Op = (ushort*)ws;               // NSPLIT*M ushorts = 16 MB
  ushort* qT = (ushort*)ws + (size_t)NSPLIT * M;
  ushort* kT = qT + M;
  ushort* vB = kT + M;
  float* y = (float*)(vB + M);
  float* Lg = y + M;
  float* stats = Lg + (size_t)NSPLIT * NB * NN;

  qkv_mm<<<dim3(NN / 32, NB, 3), 256, 0, stream>>>(x, Wq, Wk, Wv, qT, kT, vB, stats);
  attn_split<<<dim3(NN / 128, NSPLIT, NB), 256, 0, stream>>>(qT, kT, vB, Op, Lg);
  proj_mm<<<dim3(NN / 32, NB), 256, 0, stream>>>(x, Wo, Op, Lg, y, stats);
  gn_silu<<<dim3((int)(M / 1024)), 256, 0, stream>>>(y, stats, gamma, beta, out);
}